// Round 1
// baseline (249.079 us; speedup 1.0000x reference)
//
#include <hip/hip_runtime.h>
#include <hip/hip_bf16.h>

typedef __bf16 bf16;
typedef bf16 bf16x8 __attribute__((ext_vector_type(8)));
typedef bf16 bf16x4 __attribute__((ext_vector_type(4)));
typedef float f32x4 __attribute__((ext_vector_type(4)));

#define AS1 __attribute__((address_space(1)))
#define AS3 __attribute__((address_space(3)))

__device__ __forceinline__ void gload_lds16(const void* g, void* l) {
    __builtin_amdgcn_global_load_lds((const AS1 void*)g, (AS3 void*)l, 16, 0, 0);
}

__device__ __forceinline__ float tanh_fast(float x) {
    float xx = fminf(fmaxf(x, -15.0f), 15.0f);
    float e = __expf(2.0f * xx);
    return (e - 1.0f) / (e + 1.0f);
}

// ---------------------------------------------------------------------------
// Kernel 1: convert e1,e2 -> bf16 X=[e1|e2] (row-major [8192][4096]) and
// compute zs[m][c] = (1/2048) * dot(e1[r]*e2[r], W[c])  with r = 2048*m + c.
// One block per row r; c = r & 2047, m = r >> 11.
// ---------------------------------------------------------------------------
__global__ __launch_bounds__(256) void conv_x_zs(
    const float* __restrict__ e1, const float* __restrict__ e2,
    const float* __restrict__ W, bf16* __restrict__ Xb, float* __restrict__ zs)
{
    const int r = blockIdx.x;           // 0..8191
    const int t = threadIdx.x;          // 0..255, 8 elems each
    const int c = r & 2047, m = r >> 11;
    const size_t rb = (size_t)r * 2048;

    const float4* p1 = (const float4*)(e1 + rb) + t * 2;
    const float4* p2 = (const float4*)(e2 + rb) + t * 2;
    const float4* pw = (const float4*)(W + (size_t)c * 2048) + t * 2;
    float4 a0 = p1[0], a1 = p1[1];
    float4 b0 = p2[0], b1 = p2[1];
    float4 w0 = pw[0], w1 = pw[1];

    float dot = a0.x*b0.x*w0.x + a0.y*b0.y*w0.y + a0.z*b0.z*w0.z + a0.w*b0.w*w0.w
              + a1.x*b1.x*w1.x + a1.y*b1.y*w1.y + a1.z*b1.z*w1.z + a1.w*b1.w*w1.w;

    bf16x8 xa, xb;
    xa[0]=(bf16)a0.x; xa[1]=(bf16)a0.y; xa[2]=(bf16)a0.z; xa[3]=(bf16)a0.w;
    xa[4]=(bf16)a1.x; xa[5]=(bf16)a1.y; xa[6]=(bf16)a1.z; xa[7]=(bf16)a1.w;
    xb[0]=(bf16)b0.x; xb[1]=(bf16)b0.y; xb[2]=(bf16)b0.z; xb[3]=(bf16)b0.w;
    xb[4]=(bf16)b1.x; xb[5]=(bf16)b1.y; xb[6]=(bf16)b1.z; xb[7]=(bf16)b1.w;

    *(bf16x8*)(Xb + (size_t)r * 4096 + t * 8)        = xa;
    *(bf16x8*)(Xb + (size_t)r * 4096 + 2048 + t * 8) = xb;

    #pragma unroll
    for (int off = 32; off; off >>= 1) dot += __shfl_xor(dot, off);
    __shared__ float red[4];
    if ((t & 63) == 0) red[t >> 6] = dot;
    __syncthreads();
    if (t == 0) zs[m * 2048 + c] = (red[0] + red[1] + red[2] + red[3]) * (1.0f / 2048.0f);
}

// ---------------------------------------------------------------------------
// Kernel 2: V [4096][2048] f32  ->  Vt [2048][4096] bf16 (transposed, B^T)
// 64x64 tiles via LDS.
// ---------------------------------------------------------------------------
__global__ __launch_bounds__(256) void conv_vt(const float* __restrict__ V,
                                               bf16* __restrict__ Vt)
{
    __shared__ float tile[64][65];
    const int k0 = (blockIdx.x >> 5) * 64;  // 64 k-tiles
    const int c0 = (blockIdx.x & 31) * 64;  // 32 c-tiles
    const int t = threadIdx.x;
    const int rr = t >> 4;
    const int cc = (t & 15) * 4;

    #pragma unroll
    for (int r4 = 0; r4 < 4; ++r4) {
        int row = r4 * 16 + rr;
        float4 v = *(const float4*)(V + (size_t)(k0 + row) * 2048 + c0 + cc);
        tile[row][cc + 0] = v.x; tile[row][cc + 1] = v.y;
        tile[row][cc + 2] = v.z; tile[row][cc + 3] = v.w;
    }
    __syncthreads();
    #pragma unroll
    for (int r4 = 0; r4 < 4; ++r4) {
        int crow = r4 * 16 + rr;   // c index within tile
        bf16x4 o;
        o[0] = (bf16)tile[cc + 0][crow];
        o[1] = (bf16)tile[cc + 1][crow];
        o[2] = (bf16)tile[cc + 2][crow];
        o[3] = (bf16)tile[cc + 3][crow];
        *(bf16x4*)(Vt + (size_t)(c0 + crow) * 4096 + k0 + cc) = o;
    }
}

// ---------------------------------------------------------------------------
// Kernel 3: C[8192][2048] = X[8192][4096] @ V[4096][2048] (B given as Vt=B^T),
// epilogue out = tanh(acc + zs[p%4][c] + bias[c]).  128x128 tile, BK=64,
// 4 waves (2x2), 16x16x32 bf16 MFMA, global_load_lds width 16.
// ---------------------------------------------------------------------------
__global__ __launch_bounds__(256) void gemm_ep(
    const bf16* __restrict__ Xb, const bf16* __restrict__ Vt,
    const float* __restrict__ zs, const float* __restrict__ bias,
    float* __restrict__ out)
{
    __shared__ bf16 As[128 * 64];
    __shared__ bf16 Bs[128 * 64];
    const int tid  = threadIdx.x;
    const int lane = tid & 63;
    const int wave = tid >> 6;
    const int mtile = blockIdx.x >> 4;   // 64 row tiles
    const int ntile = blockIdx.x & 15;   // 16 col tiles
    const int row0 = mtile * 128, col0 = ntile * 128;
    const int wm = (wave >> 1) * 64, wn = (wave & 1) * 64;

    f32x4 acc[4][4] = {};

    // staging: per round r (0..3), thread covers LDS elems r*2048 + tid*8
    const int srow = tid >> 3;          // 0..31
    const int scol = (tid & 7) * 8;     // 0..56
    const bf16* Ag = Xb + (size_t)(row0 + srow) * 4096 + scol;
    const bf16* Bg = Vt + (size_t)(col0 + srow) * 4096 + scol;
    char* AsB = (char*)As + tid * 16;
    char* BsB = (char*)Bs + tid * 16;

    const int lr = lane & 15;
    const int lk = (lane >> 4) * 8;

    for (int kt = 0; kt < 64; ++kt) {
        const int kof = kt * 64;
        #pragma unroll
        for (int r = 0; r < 4; ++r)
            gload_lds16(Ag + (size_t)(r * 32) * 4096 + kof, AsB + r * 4096);
        #pragma unroll
        for (int r = 0; r < 4; ++r)
            gload_lds16(Bg + (size_t)(r * 32) * 4096 + kof, BsB + r * 4096);
        __syncthreads();   // drains vmcnt before barrier (compiler-inserted)

        #pragma unroll
        for (int kk = 0; kk < 2; ++kk) {
            bf16x8 af[4], bfr[4];
            #pragma unroll
            for (int i = 0; i < 4; ++i)
                af[i] = *(const bf16x8*)&As[(wm + i * 16 + lr) * 64 + kk * 32 + lk];
            #pragma unroll
            for (int j = 0; j < 4; ++j)
                bfr[j] = *(const bf16x8*)&Bs[(wn + j * 16 + lr) * 64 + kk * 32 + lk];
            #pragma unroll
            for (int i = 0; i < 4; ++i)
                #pragma unroll
                for (int j = 0; j < 4; ++j)
                    acc[i][j] = __builtin_amdgcn_mfma_f32_16x16x32_bf16(
                        af[i], bfr[j], acc[i][j], 0, 0, 0);
        }
        __syncthreads();   // protect LDS overwrite next iteration
    }

    // epilogue: out = tanh(acc + zs[p%4][c] + bias[c])
    // C/D layout (m89): col = lane&15, row = (lane>>4)*4 + q.
    // p%4 == q here since row0, wm, i*16, (lane>>4)*4 are all multiples of 4.
    const int lq = lane >> 4;
    #pragma unroll
    for (int j = 0; j < 4; ++j) {
        const int c = col0 + wn + j * 16 + lr;
        const float bb = bias[c];
        float zrow[4];
        #pragma unroll
        for (int q = 0; q < 4; ++q) zrow[q] = zs[q * 2048 + c] + bb;
        #pragma unroll
        for (int i = 0; i < 4; ++i) {
            const int pbase = row0 + wm + i * 16 + lq * 4;
            #pragma unroll
            for (int q = 0; q < 4; ++q)
                out[(size_t)(pbase + q) * 2048 + c] = tanh_fast(acc[i][j][q] + zrow[q]);
        }
    }
}

// ---------------------------------------------------------------------------
extern "C" void kernel_launch(void* const* d_in, const int* in_sizes, int n_in,
                              void* d_out, int out_size, void* d_ws, size_t ws_size,
                              hipStream_t stream) {
    const float* e1 = (const float*)d_in[0];   // (8192, 2048)
    const float* e2 = (const float*)d_in[1];   // (8192, 2048)
    const float* W  = (const float*)d_in[2];   // (2048, 2048)
    const float* V  = (const float*)d_in[3];   // (4096, 2048)
    const float* b  = (const float*)d_in[4];   // (2048,)
    float* out = (float*)d_out;                // (8192, 2048) f32

    char* ws = (char*)d_ws;
    bf16*  Xb = (bf16*)ws;                                  // 64 MiB
    bf16*  Vt = (bf16*)(ws + (size_t)64 * 1024 * 1024);     // 16 MiB
    float* zs = (float*)(ws + (size_t)80 * 1024 * 1024);    // 32 KiB

    conv_x_zs<<<8192, 256, 0, stream>>>(e1, e2, W, Xb, zs);
    conv_vt<<<2048, 256, 0, stream>>>(V, Vt);
    gemm_ep<<<1024, 256, 0, stream>>>(Xb, Vt, zs, b, out);
}

// Round 2
// 215.132 us; speedup vs baseline: 1.1578x; 1.1578x over previous
//
#include <hip/hip_runtime.h>
#include <hip/hip_bf16.h>

typedef __bf16 bf16;
typedef bf16 bf16x8 __attribute__((ext_vector_type(8)));
typedef bf16 bf16x4 __attribute__((ext_vector_type(4)));
typedef float f32x4 __attribute__((ext_vector_type(4)));

#define AS1 __attribute__((address_space(1)))
#define AS3 __attribute__((address_space(3)))

__device__ __forceinline__ void gload_lds16(const void* g, void* l) {
    __builtin_amdgcn_global_load_lds((const AS1 void*)g, (AS3 void*)l, 16, 0, 0);
}

__device__ __forceinline__ float tanh_fast(float x) {
    float xx = fminf(fmaxf(x, -15.0f), 15.0f);
    float e = __expf(2.0f * xx);
    return (e - 1.0f) / (e + 1.0f);
}

// ---------------------------------------------------------------------------
// Kernel 1: convert e1,e2 -> bf16 X=[e1|e2] (row-major [8192][4096]) and
// compute zs[m][c] = (1/2048) * dot(e1[r]*e2[r], W[c])  with r = 2048*m + c.
// ---------------------------------------------------------------------------
__global__ __launch_bounds__(256) void conv_x_zs(
    const float* __restrict__ e1, const float* __restrict__ e2,
    const float* __restrict__ W, bf16* __restrict__ Xb, float* __restrict__ zs)
{
    const int r = blockIdx.x;           // 0..8191
    const int t = threadIdx.x;          // 0..255, 8 elems each
    const int c = r & 2047, m = r >> 11;
    const size_t rb = (size_t)r * 2048;

    const float4* p1 = (const float4*)(e1 + rb) + t * 2;
    const float4* p2 = (const float4*)(e2 + rb) + t * 2;
    const float4* pw = (const float4*)(W + (size_t)c * 2048) + t * 2;
    float4 a0 = p1[0], a1 = p1[1];
    float4 b0 = p2[0], b1 = p2[1];
    float4 w0 = pw[0], w1 = pw[1];

    float dot = a0.x*b0.x*w0.x + a0.y*b0.y*w0.y + a0.z*b0.z*w0.z + a0.w*b0.w*w0.w
              + a1.x*b1.x*w1.x + a1.y*b1.y*w1.y + a1.z*b1.z*w1.z + a1.w*b1.w*w1.w;

    bf16x8 xa, xb;
    xa[0]=(bf16)a0.x; xa[1]=(bf16)a0.y; xa[2]=(bf16)a0.z; xa[3]=(bf16)a0.w;
    xa[4]=(bf16)a1.x; xa[5]=(bf16)a1.y; xa[6]=(bf16)a1.z; xa[7]=(bf16)a1.w;
    xb[0]=(bf16)b0.x; xb[1]=(bf16)b0.y; xb[2]=(bf16)b0.z; xb[3]=(bf16)b0.w;
    xb[4]=(bf16)b1.x; xb[5]=(bf16)b1.y; xb[6]=(bf16)b1.z; xb[7]=(bf16)b1.w;

    *(bf16x8*)(Xb + (size_t)r * 4096 + t * 8)        = xa;
    *(bf16x8*)(Xb + (size_t)r * 4096 + 2048 + t * 8) = xb;

    #pragma unroll
    for (int off = 32; off; off >>= 1) dot += __shfl_xor(dot, off);
    __shared__ float red[4];
    if ((t & 63) == 0) red[t >> 6] = dot;
    __syncthreads();
    if (t == 0) zs[m * 2048 + c] = (red[0] + red[1] + red[2] + red[3]) * (1.0f / 2048.0f);
}

// ---------------------------------------------------------------------------
// Kernel 2: V [4096][2048] f32  ->  Vt [2048][4096] bf16 (transposed, B^T)
// ---------------------------------------------------------------------------
__global__ __launch_bounds__(256) void conv_vt(const float* __restrict__ V,
                                               bf16* __restrict__ Vt)
{
    __shared__ float tile[64][65];
    const int k0 = (blockIdx.x >> 5) * 64;  // 64 k-tiles
    const int c0 = (blockIdx.x & 31) * 64;  // 32 c-tiles
    const int t = threadIdx.x;
    const int rr = t >> 4;
    const int cc = (t & 15) * 4;

    #pragma unroll
    for (int r4 = 0; r4 < 4; ++r4) {
        int row = r4 * 16 + rr;
        float4 v = *(const float4*)(V + (size_t)(k0 + row) * 2048 + c0 + cc);
        tile[row][cc + 0] = v.x; tile[row][cc + 1] = v.y;
        tile[row][cc + 2] = v.z; tile[row][cc + 3] = v.w;
    }
    __syncthreads();
    #pragma unroll
    for (int r4 = 0; r4 < 4; ++r4) {
        int crow = r4 * 16 + rr;   // c index within tile
        bf16x4 o;
        o[0] = (bf16)tile[cc + 0][crow];
        o[1] = (bf16)tile[cc + 1][crow];
        o[2] = (bf16)tile[cc + 2][crow];
        o[3] = (bf16)tile[cc + 3][crow];
        *(bf16x4*)(Vt + (size_t)(c0 + crow) * 4096 + k0 + cc) = o;
    }
}

// ---------------------------------------------------------------------------
// Kernel 3: C = X @ Vt^T with fused epilogue tanh(acc + zs[p%4][c] + bias[c]).
// 128x128 tile, BK=64, 4 waves, 16x16x32 bf16 MFMA, global_load_lds width 16.
// T2 st-swizzle: LDS phys byte = row*128 + (cb ^ ((row&7)<<4)); applied as
// inverse-swizzled GLOBAL source (gload_lds writes linearly) + swizzled
// ds_read address (rule #21: both-sides-or-neither).
// ---------------------------------------------------------------------------
__global__ __launch_bounds__(256) void gemm_ep(
    const bf16* __restrict__ Xb, const bf16* __restrict__ Vt,
    const float* __restrict__ zs, const float* __restrict__ bias,
    float* __restrict__ out)
{
    __shared__ bf16 As[128 * 64];
    __shared__ bf16 Bs[128 * 64];
    const int tid  = threadIdx.x;
    const int lane = tid & 63;
    const int wave = tid >> 6;
    const int mtile = blockIdx.x >> 4;   // 64 row tiles
    const int ntile = blockIdx.x & 15;   // 16 col tiles
    const int row0 = mtile * 128, col0 = ntile * 128;
    const int wm = (wave >> 1) * 64, wn = (wave & 1) * 64;

    f32x4 acc[4][4] = {};

    // staging: thread covers LDS phys bytes tid*16 + r*4096 (rows step by 32,
    // 32 ≡ 0 mod 8, so the swizzled source column is constant across r).
    const int srow = tid >> 3;                                // 0..31
    const int scb  = ((tid & 7) * 16) ^ ((srow & 7) << 4);    // swizzled byte col
    const bf16* Ag = Xb + (size_t)(row0 + srow) * 4096 + (scb >> 1);
    const bf16* Bg = Vt + (size_t)(col0 + srow) * 4096 + (scb >> 1);
    char* AsB = (char*)As + tid * 16;
    char* BsB = (char*)Bs + tid * 16;

    const int lr  = lane & 15;
    const int lkb = (lane >> 4) * 16;   // byte offset of this lane's k-slice

    for (int kt = 0; kt < 64; ++kt) {
        const int kof = kt * 64;
        #pragma unroll
        for (int r = 0; r < 4; ++r)
            gload_lds16(Ag + (size_t)(r * 32) * 4096 + kof, AsB + r * 4096);
        #pragma unroll
        for (int r = 0; r < 4; ++r)
            gload_lds16(Bg + (size_t)(r * 32) * 4096 + kof, BsB + r * 4096);
        __syncthreads();

        #pragma unroll
        for (int kk = 0; kk < 2; ++kk) {
            const int cb = kk * 64 + lkb;   // logical byte column in tile
            bf16x8 af[4], bfr[4];
            #pragma unroll
            for (int i = 0; i < 4; ++i) {
                const int R = wm + i * 16 + lr;
                af[i] = *(const bf16x8*)((const char*)As +
                         R * 128 + (cb ^ ((R & 7) << 4)));
            }
            #pragma unroll
            for (int j = 0; j < 4; ++j) {
                const int R = wn + j * 16 + lr;
                bfr[j] = *(const bf16x8*)((const char*)Bs +
                          R * 128 + (cb ^ ((R & 7) << 4)));
            }
            #pragma unroll
            for (int i = 0; i < 4; ++i)
                #pragma unroll
                for (int j = 0; j < 4; ++j)
                    acc[i][j] = __builtin_amdgcn_mfma_f32_16x16x32_bf16(
                        af[i], bfr[j], acc[i][j], 0, 0, 0);
        }
        __syncthreads();
    }

    // epilogue: out = tanh(acc + zs[p%4][c] + bias[c])
    // C/D layout (m89): col = lane&15, row = (lane>>4)*4 + q; p%4 == q here.
    const int lq = lane >> 4;
    #pragma unroll
    for (int j = 0; j < 4; ++j) {
        const int c = col0 + wn + j * 16 + lr;
        const float bb = bias[c];
        float zrow[4];
        #pragma unroll
        for (int q = 0; q < 4; ++q) zrow[q] = zs[q * 2048 + c] + bb;
        #pragma unroll
        for (int i = 0; i < 4; ++i) {
            const int pbase = row0 + wm + i * 16 + lq * 4;
            #pragma unroll
            for (int q = 0; q < 4; ++q)
                out[(size_t)(pbase + q) * 2048 + c] = tanh_fast(acc[i][j][q] + zrow[q]);
        }
    }
}

// ---------------------------------------------------------------------------
extern "C" void kernel_launch(void* const* d_in, const int* in_sizes, int n_in,
                              void* d_out, int out_size, void* d_ws, size_t ws_size,
                              hipStream_t stream) {
    const float* e1 = (const float*)d_in[0];   // (8192, 2048)
    const float* e2 = (const float*)d_in[1];   // (8192, 2048)
    const float* W  = (const float*)d_in[2];   // (2048, 2048)
    const float* V  = (const float*)d_in[3];   // (4096, 2048)
    const float* b  = (const float*)d_in[4];   // (2048,)
    float* out = (float*)d_out;                // (8192, 2048) f32

    char* ws = (char*)d_ws;
    bf16*  Xb = (bf16*)ws;                                  // 64 MiB
    bf16*  Vt = (bf16*)(ws + (size_t)64 * 1024 * 1024);     // 16 MiB
    float* zs = (float*)(ws + (size_t)80 * 1024 * 1024);    // 32 KiB

    conv_x_zs<<<8192, 256, 0, stream>>>(e1, e2, W, Xb, zs);
    conv_vt<<<2048, 256, 0, stream>>>(V, Vt);
    gemm_ep<<<1024, 256, 0, stream>>>(Xb, Vt, zs, b, out);
}

// Round 3
// 185.018 us; speedup vs baseline: 1.3462x; 1.1628x over previous
//
#include <hip/hip_runtime.h>
#include <hip/hip_bf16.h>

typedef __bf16 bf16;
typedef bf16 bf16x8 __attribute__((ext_vector_type(8)));
typedef bf16 bf16x4 __attribute__((ext_vector_type(4)));
typedef float f32x4 __attribute__((ext_vector_type(4)));

#define AS1 __attribute__((address_space(1)))
#define AS3 __attribute__((address_space(3)))

__device__ __forceinline__ void gload_lds16(const void* g, void* l) {
    __builtin_amdgcn_global_load_lds((const AS1 void*)g, (AS3 void*)l, 16, 0, 0);
}

__device__ __forceinline__ float tanh_fast(float x) {
    float xx = fminf(fmaxf(x, -15.0f), 15.0f);
    float e = __expf(2.0f * xx);
    return (e - 1.0f) / (e + 1.0f);
}

// ---------------------------------------------------------------------------
// Kernel 1: convert e1,e2 -> bf16 X=[e1|e2] (row-major [8192][4096]) and
// compute zs[m][c] = (1/2048) * dot(e1[r]*e2[r], W[c])  with r = 2048*m + c.
// ---------------------------------------------------------------------------
__global__ __launch_bounds__(256) void conv_x_zs(
    const float* __restrict__ e1, const float* __restrict__ e2,
    const float* __restrict__ W, bf16* __restrict__ Xb, float* __restrict__ zs)
{
    const int r = blockIdx.x;           // 0..8191
    const int t = threadIdx.x;          // 0..255, 8 elems each
    const int c = r & 2047, m = r >> 11;
    const size_t rb = (size_t)r * 2048;

    const float4* p1 = (const float4*)(e1 + rb) + t * 2;
    const float4* p2 = (const float4*)(e2 + rb) + t * 2;
    const float4* pw = (const float4*)(W + (size_t)c * 2048) + t * 2;
    float4 a0 = p1[0], a1 = p1[1];
    float4 b0 = p2[0], b1 = p2[1];
    float4 w0 = pw[0], w1 = pw[1];

    float dot = a0.x*b0.x*w0.x + a0.y*b0.y*w0.y + a0.z*b0.z*w0.z + a0.w*b0.w*w0.w
              + a1.x*b1.x*w1.x + a1.y*b1.y*w1.y + a1.z*b1.z*w1.z + a1.w*b1.w*w1.w;

    bf16x8 xa, xb;
    xa[0]=(bf16)a0.x; xa[1]=(bf16)a0.y; xa[2]=(bf16)a0.z; xa[3]=(bf16)a0.w;
    xa[4]=(bf16)a1.x; xa[5]=(bf16)a1.y; xa[6]=(bf16)a1.z; xa[7]=(bf16)a1.w;
    xb[0]=(bf16)b0.x; xb[1]=(bf16)b0.y; xb[2]=(bf16)b0.z; xb[3]=(bf16)b0.w;
    xb[4]=(bf16)b1.x; xb[5]=(bf16)b1.y; xb[6]=(bf16)b1.z; xb[7]=(bf16)b1.w;

    *(bf16x8*)(Xb + (size_t)r * 4096 + t * 8)        = xa;
    *(bf16x8*)(Xb + (size_t)r * 4096 + 2048 + t * 8) = xb;

    #pragma unroll
    for (int off = 32; off; off >>= 1) dot += __shfl_xor(dot, off);
    __shared__ float red[4];
    if ((t & 63) == 0) red[t >> 6] = dot;
    __syncthreads();
    if (t == 0) zs[m * 2048 + c] = (red[0] + red[1] + red[2] + red[3]) * (1.0f / 2048.0f);
}

// ---------------------------------------------------------------------------
// Kernel 2: V [4096][2048] f32  ->  Vt [2048][4096] bf16 (transposed, B^T)
// ---------------------------------------------------------------------------
__global__ __launch_bounds__(256) void conv_vt(const float* __restrict__ V,
                                               bf16* __restrict__ Vt)
{
    __shared__ float tile[64][65];
    const int k0 = (blockIdx.x >> 5) * 64;  // 64 k-tiles
    const int c0 = (blockIdx.x & 31) * 64;  // 32 c-tiles
    const int t = threadIdx.x;
    const int rr = t >> 4;
    const int cc = (t & 15) * 4;

    #pragma unroll
    for (int r4 = 0; r4 < 4; ++r4) {
        int row = r4 * 16 + rr;
        float4 v = *(const float4*)(V + (size_t)(k0 + row) * 2048 + c0 + cc);
        tile[row][cc + 0] = v.x; tile[row][cc + 1] = v.y;
        tile[row][cc + 2] = v.z; tile[row][cc + 3] = v.w;
    }
    __syncthreads();
    #pragma unroll
    for (int r4 = 0; r4 < 4; ++r4) {
        int crow = r4 * 16 + rr;   // c index within tile
        bf16x4 o;
        o[0] = (bf16)tile[cc + 0][crow];
        o[1] = (bf16)tile[cc + 1][crow];
        o[2] = (bf16)tile[cc + 2][crow];
        o[3] = (bf16)tile[cc + 3][crow];
        *(bf16x4*)(Vt + (size_t)(c0 + crow) * 4096 + k0 + cc) = o;
    }
}

// ---------------------------------------------------------------------------
// Kernel 3: 256x256-tile 8-phase GEMM (T2 swizzle + T3/T4 counted vmcnt + T5
// setprio), fused epilogue tanh(acc + zs[p%4][c] + bias[c]).
// 512 threads = 8 waves (2M x 4N); per-wave output 128x64; BK=64.
// LDS 128 KiB dynamic: [buf0: A 32K | B 32K][buf1: A 32K | B 32K].
// Swizzle: phys byte = R*128 + (cb ^ ((R&7)<<4)); gload_lds writes linearly,
// so the global SOURCE is inverse-swizzled (same involution) per rule #21.
// Pipeline: tile t+2 staged in phase 4 (after all reads of its buffer have
// been register-captured, guaranteed by phase-3's end barrier); vmcnt(8)
// after phase-4 MFMA leaves those 8 loads in flight across the barrier.
// ---------------------------------------------------------------------------
__global__ __launch_bounds__(512, 2) void gemm_ep(
    const bf16* __restrict__ Xb, const bf16* __restrict__ Vt,
    const float* __restrict__ zs, const float* __restrict__ bias,
    float* __restrict__ out)
{
    extern __shared__ char smem[];     // 131072 bytes
    const int tid  = threadIdx.x;
    const int lane = tid & 63;
    const int wid  = tid >> 6;
    const int wr = wid >> 2, wc = wid & 3;
    const int mtile = blockIdx.x >> 3;   // 32 row tiles
    const int ntile = blockIdx.x & 7;    // 8 col tiles (ntile == XCD id)
    const int row0 = mtile * 256, col0 = ntile * 256;

    // staging: thread covers LDS phys bytes tid*16 + r*8192 (rows step 64;
    // 64 % 8 == 0 so the swizzled source column is constant across r).
    const int srow = tid >> 3;                               // 0..63
    const int scb  = ((tid & 7) * 16) ^ ((srow & 7) << 4);   // swizzled byte col
    const bf16* Abase = Xb + (size_t)(row0 + srow) * 4096 + (scb >> 1);
    const bf16* Bbase = Vt + (size_t)(col0 + srow) * 4096 + (scb >> 1);

    const int lr  = lane & 15;
    const int lkb = (lane >> 4) * 16;   // byte offset of this lane's k-slice

    f32x4 acc[2][2][4][2] = {};   // [qm][qn][i][j]
    bf16x8 aA[4][2];              // current qm half: [i][ks]
    bf16x8 bB[2][2][2];           // [qn][j][ks], held all iteration

    auto stage = [&](int c, int kt) {
        char* Al = smem + c * 65536 + tid * 16;
        char* Bl = smem + c * 65536 + 32768 + tid * 16;
        const bf16* Ag = Abase + (size_t)kt * 64;
        const bf16* Bg = Bbase + (size_t)kt * 64;
        #pragma unroll
        for (int r = 0; r < 4; ++r) gload_lds16(Ag + (size_t)r * 262144, Al + r * 8192);
        #pragma unroll
        for (int r = 0; r < 4; ++r) gload_lds16(Bg + (size_t)r * 262144, Bl + r * 8192);
    };

    // prologue: tiles 0,1 in flight; wait tile 0 (8 of 16 outstanding drain)
    stage(0, 0);
    stage(1, 1);
    asm volatile("s_waitcnt vmcnt(8)" ::: "memory");
    __builtin_amdgcn_s_barrier();

    #pragma unroll 2
    for (int t = 0; t < 64; ++t) {
        const int c = t & 1;
        const char* Ab = smem + c * 65536;
        const char* Bb = smem + c * 65536 + 32768;

        auto ldA = [&](int qm, int i, int ks) -> bf16x8 {
            const int R = wr * 128 + qm * 64 + i * 16 + lr;
            const int cb = ks * 64 + lkb;
            return *(const bf16x8*)(Ab + R * 128 + (cb ^ ((R & 7) << 4)));
        };
        auto ldB = [&](int qn, int j, int ks) -> bf16x8 {
            const int R = wc * 64 + qn * 32 + j * 16 + lr;
            const int cb = ks * 64 + lkb;
            return *(const bf16x8*)(Bb + R * 128 + (cb ^ ((R & 7) << 4)));
        };

        // ---- Phase 1: quadrant (0,0) — read A half 0 (8) + B half 0 (4)
        #pragma unroll
        for (int i = 0; i < 4; ++i) { aA[i][0] = ldA(0, i, 0); aA[i][1] = ldA(0, i, 1); }
        #pragma unroll
        for (int j = 0; j < 2; ++j) { bB[0][j][0] = ldB(0, j, 0); bB[0][j][1] = ldB(0, j, 1); }
        __builtin_amdgcn_s_barrier();
        __builtin_amdgcn_s_setprio(1);
        #pragma unroll
        for (int ks = 0; ks < 2; ++ks)
            #pragma unroll
            for (int i = 0; i < 4; ++i)
                #pragma unroll
                for (int j = 0; j < 2; ++j)
                    acc[0][0][i][j] = __builtin_amdgcn_mfma_f32_16x16x32_bf16(
                        aA[i][ks], bB[0][j][ks], acc[0][0][i][j], 0, 0, 0);
        __builtin_amdgcn_s_setprio(0);
        __builtin_amdgcn_s_barrier();

        // ---- Phase 2: quadrant (0,1) — read B half 1 (4)
        #pragma unroll
        for (int j = 0; j < 2; ++j) { bB[1][j][0] = ldB(1, j, 0); bB[1][j][1] = ldB(1, j, 1); }
        __builtin_amdgcn_s_barrier();
        __builtin_amdgcn_s_setprio(1);
        #pragma unroll
        for (int ks = 0; ks < 2; ++ks)
            #pragma unroll
            for (int i = 0; i < 4; ++i)
                #pragma unroll
                for (int j = 0; j < 2; ++j)
                    acc[0][1][i][j] = __builtin_amdgcn_mfma_f32_16x16x32_bf16(
                        aA[i][ks], bB[1][j][ks], acc[0][1][i][j], 0, 0, 0);
        __builtin_amdgcn_s_setprio(0);
        __builtin_amdgcn_s_barrier();

        // ---- Phase 3: quadrant (1,1) — read A half 1 (8), reuse B half 1
        #pragma unroll
        for (int i = 0; i < 4; ++i) { aA[i][0] = ldA(1, i, 0); aA[i][1] = ldA(1, i, 1); }
        __builtin_amdgcn_s_barrier();
        __builtin_amdgcn_s_setprio(1);
        #pragma unroll
        for (int ks = 0; ks < 2; ++ks)
            #pragma unroll
            for (int i = 0; i < 4; ++i)
                #pragma unroll
                for (int j = 0; j < 2; ++j)
                    acc[1][1][i][j] = __builtin_amdgcn_mfma_f32_16x16x32_bf16(
                        aA[i][ks], bB[1][j][ks], acc[1][1][i][j], 0, 0, 0);
        __builtin_amdgcn_s_setprio(0);
        __builtin_amdgcn_s_barrier();

        // ---- Phase 4: quadrant (1,0) — no reads; stage tile t+2 into buf c
        // (all reads of buf c were register-captured before phase-3's end
        // barrier). Counted vmcnt(8) after MFMA leaves tile t+2 in flight.
        if (t < 62) stage(c, t + 2);
        __builtin_amdgcn_s_barrier();
        __builtin_amdgcn_s_setprio(1);
        #pragma unroll
        for (int ks = 0; ks < 2; ++ks)
            #pragma unroll
            for (int i = 0; i < 4; ++i)
                #pragma unroll
                for (int j = 0; j < 2; ++j)
                    acc[1][0][i][j] = __builtin_amdgcn_mfma_f32_16x16x32_bf16(
                        aA[i][ks], bB[0][j][ks], acc[1][0][i][j], 0, 0, 0);
        __builtin_amdgcn_s_setprio(0);
        if (t < 62)       asm volatile("s_waitcnt vmcnt(8)" ::: "memory");
        else if (t == 62) asm volatile("s_waitcnt vmcnt(0)" ::: "memory");
        __builtin_amdgcn_s_barrier();
    }

    // epilogue: out = tanh(acc + zs[p%4][c] + bias[c])
    // C/D layout (m89): col = lane&15, row = (lane>>4)*4 + q; p%4 == q here
    // (row0, wr*128, qm*64, i*16, lq*4 all multiples of 4).
    const int lq = lane >> 4;
    #pragma unroll
    for (int qn = 0; qn < 2; ++qn)
        #pragma unroll
        for (int j = 0; j < 2; ++j) {
            const int ccol = col0 + wc * 64 + qn * 32 + j * 16 + lr;
            const float bb = bias[ccol];
            float zrow[4];
            #pragma unroll
            for (int q = 0; q < 4; ++q) zrow[q] = zs[q * 2048 + ccol] + bb;
            #pragma unroll
            for (int qm = 0; qm < 2; ++qm)
                #pragma unroll
                for (int i = 0; i < 4; ++i) {
                    const int prow = row0 + wr * 128 + qm * 64 + i * 16 + lq * 4;
                    #pragma unroll
                    for (int q = 0; q < 4; ++q)
                        out[(size_t)(prow + q) * 2048 + ccol] =
                            tanh_fast(acc[qm][qn][i][j][q] + zrow[q]);
                }
        }
}

// ---------------------------------------------------------------------------
extern "C" void kernel_launch(void* const* d_in, const int* in_sizes, int n_in,
                              void* d_out, int out_size, void* d_ws, size_t ws_size,
                              hipStream_t stream) {
    const float* e1 = (const float*)d_in[0];   // (8192, 2048)
    const float* e2 = (const float*)d_in[1];   // (8192, 2048)
    const float* W  = (const float*)d_in[2];   // (2048, 2048)
    const float* V  = (const float*)d_in[3];   // (4096, 2048)
    const float* b  = (const float*)d_in[4];   // (2048,)
    float* out = (float*)d_out;                // (8192, 2048) f32

    char* ws = (char*)d_ws;
    bf16*  Xb = (bf16*)ws;                                  // 64 MiB
    bf16*  Vt = (bf16*)(ws + (size_t)64 * 1024 * 1024);     // 16 MiB
    float* zs = (float*)(ws + (size_t)80 * 1024 * 1024);    // 32 KiB

    conv_x_zs<<<8192, 256, 0, stream>>>(e1, e2, W, Xb, zs);
    conv_vt<<<2048, 256, 0, stream>>>(V, Vt);

    hipFuncSetAttribute((const void*)gemm_ep,
                        hipFuncAttributeMaxDynamicSharedMemorySize, 131072);
    gemm_ep<<<256, 512, 131072, stream>>>(Xb, Vt, zs, b, out);
}

// Round 4
// 169.682 us; speedup vs baseline: 1.4679x; 1.0904x over previous
//
#include <hip/hip_runtime.h>
#include <hip/hip_bf16.h>

typedef __bf16 bf16;
typedef bf16 bf16x8 __attribute__((ext_vector_type(8)));
typedef bf16 bf16x4 __attribute__((ext_vector_type(4)));
typedef float f32x4 __attribute__((ext_vector_type(4)));

#define AS1 __attribute__((address_space(1)))
#define AS3 __attribute__((address_space(3)))

__device__ __forceinline__ void gload_lds16(const void* g, void* l) {
    __builtin_amdgcn_global_load_lds((const AS1 void*)g, (AS3 void*)l, 16, 0, 0);
}

__device__ __forceinline__ float tanh_fast(float x) {
    float xx = fminf(fmaxf(x, -15.0f), 15.0f);
    float e = __expf(2.0f * xx);
    return (e - 1.0f) / (e + 1.0f);
}

// ---------------------------------------------------------------------------
// Kernel 1: convert e1,e2 -> bf16 X=[e1|e2] (row-major [8192][4096]) and
// compute zs[m][c] = (1/2048) * dot(e1[r]*e2[r], W[c])  with r = 2048*m + c.
// ---------------------------------------------------------------------------
__global__ __launch_bounds__(256) void conv_x_zs(
    const float* __restrict__ e1, const float* __restrict__ e2,
    const float* __restrict__ W, bf16* __restrict__ Xb, float* __restrict__ zs)
{
    const int r = blockIdx.x;           // 0..8191
    const int t = threadIdx.x;          // 0..255, 8 elems each
    const int c = r & 2047, m = r >> 11;
    const size_t rb = (size_t)r * 2048;

    const float4* p1 = (const float4*)(e1 + rb) + t * 2;
    const float4* p2 = (const float4*)(e2 + rb) + t * 2;
    const float4* pw = (const float4*)(W + (size_t)c * 2048) + t * 2;
    float4 a0 = p1[0], a1 = p1[1];
    float4 b0 = p2[0], b1 = p2[1];
    float4 w0 = pw[0], w1 = pw[1];

    float dot = a0.x*b0.x*w0.x + a0.y*b0.y*w0.y + a0.z*b0.z*w0.z + a0.w*b0.w*w0.w
              + a1.x*b1.x*w1.x + a1.y*b1.y*w1.y + a1.z*b1.z*w1.z + a1.w*b1.w*w1.w;

    bf16x8 xa, xb;
    xa[0]=(bf16)a0.x; xa[1]=(bf16)a0.y; xa[2]=(bf16)a0.z; xa[3]=(bf16)a0.w;
    xa[4]=(bf16)a1.x; xa[5]=(bf16)a1.y; xa[6]=(bf16)a1.z; xa[7]=(bf16)a1.w;
    xb[0]=(bf16)b0.x; xb[1]=(bf16)b0.y; xb[2]=(bf16)b0.z; xb[3]=(bf16)b0.w;
    xb[4]=(bf16)b1.x; xb[5]=(bf16)b1.y; xb[6]=(bf16)b1.z; xb[7]=(bf16)b1.w;

    *(bf16x8*)(Xb + (size_t)r * 4096 + t * 8)        = xa;
    *(bf16x8*)(Xb + (size_t)r * 4096 + 2048 + t * 8) = xb;

    #pragma unroll
    for (int off = 32; off; off >>= 1) dot += __shfl_xor(dot, off);
    __shared__ float red[4];
    if ((t & 63) == 0) red[t >> 6] = dot;
    __syncthreads();
    if (t == 0) zs[m * 2048 + c] = (red[0] + red[1] + red[2] + red[3]) * (1.0f / 2048.0f);
}

// ---------------------------------------------------------------------------
// Kernel 2: V [4096][2048] f32  ->  Vt [2048][4096] bf16 (transposed, B^T)
// ---------------------------------------------------------------------------
__global__ __launch_bounds__(256) void conv_vt(const float* __restrict__ V,
                                               bf16* __restrict__ Vt)
{
    __shared__ float tile[64][65];
    const int k0 = (blockIdx.x >> 5) * 64;  // 64 k-tiles
    const int c0 = (blockIdx.x & 31) * 64;  // 32 c-tiles
    const int t = threadIdx.x;
    const int rr = t >> 4;
    const int cc = (t & 15) * 4;

    #pragma unroll
    for (int r4 = 0; r4 < 4; ++r4) {
        int row = r4 * 16 + rr;
        float4 v = *(const float4*)(V + (size_t)(k0 + row) * 2048 + c0 + cc);
        tile[row][cc + 0] = v.x; tile[row][cc + 1] = v.y;
        tile[row][cc + 2] = v.z; tile[row][cc + 3] = v.w;
    }
    __syncthreads();
    #pragma unroll
    for (int r4 = 0; r4 < 4; ++r4) {
        int crow = r4 * 16 + rr;   // c index within tile
        bf16x4 o;
        o[0] = (bf16)tile[cc + 0][crow];
        o[1] = (bf16)tile[cc + 1][crow];
        o[2] = (bf16)tile[cc + 2][crow];
        o[3] = (bf16)tile[cc + 3][crow];
        *(bf16x4*)(Vt + (size_t)(c0 + crow) * 4096 + k0 + cc) = o;
    }
}

// ---------------------------------------------------------------------------
// Kernel 3: 256x256-tile GEMM, 2-barriers-per-K-step schedule.
// Window 1: {rd A0,B0 | mfma q00 | rd B1 | mfma q01 | rd A1 (WAR-pinned after
// q01) | mfma q11} barrier.  Window 2: {stage t+2 | mfma q10 | vmcnt(8)}
// barrier.  Reads drain under MFMA clusters via compiler fine-grained lgkmcnt;
// only 2 sync points per K-step (vs 8) so waves skew and keep both pipes busy.
// Race-safety: all buf-c reads complete before barrier-1 (lgkm per-wave,
// barrier cross-wave); stage(t+2,buf c) issued only after barrier-1; tile t+1
// readiness enforced by counted vmcnt(8) before barrier-2 (8 newest = t+2's).
// T2 swizzle: phys byte = R*128 + (cb ^ ((R&7)<<4)), gload_lds writes linear,
// global source inverse-swizzled (rule #21).
// ---------------------------------------------------------------------------
__global__ __launch_bounds__(512, 2) void gemm_ep(
    const bf16* __restrict__ Xb, const bf16* __restrict__ Vt,
    const float* __restrict__ zs, const float* __restrict__ bias,
    float* __restrict__ out)
{
    extern __shared__ char smem[];     // 131072 bytes
    const int tid  = threadIdx.x;
    const int lane = tid & 63;
    const int wid  = tid >> 6;
    const int wr = wid >> 2, wc = wid & 3;
    const int mtile = blockIdx.x >> 3;   // 32 row tiles
    const int ntile = blockIdx.x & 7;    // 8 col tiles (ntile == XCD id)
    const int row0 = mtile * 256, col0 = ntile * 256;

    const int srow = tid >> 3;                               // 0..63
    const int scb  = ((tid & 7) * 16) ^ ((srow & 7) << 4);   // swizzled byte col
    const bf16* Abase = Xb + (size_t)(row0 + srow) * 4096 + (scb >> 1);
    const bf16* Bbase = Vt + (size_t)(col0 + srow) * 4096 + (scb >> 1);

    const int lr  = lane & 15;
    const int lkb = (lane >> 4) * 16;

    f32x4 acc[2][2][4][2] = {};   // [qm][qn][i][j]
    bf16x8 aA[4][2];              // current A half (reused q00/q01 -> q11/q10)
    bf16x8 bB[2][2][2];           // [qn][j][ks], both halves live all K-step

    auto stage = [&](int c, int kt) {
        char* Al = smem + c * 65536 + tid * 16;
        char* Bl = smem + c * 65536 + 32768 + tid * 16;
        const bf16* Ag = Abase + (size_t)kt * 64;
        const bf16* Bg = Bbase + (size_t)kt * 64;
        #pragma unroll
        for (int r = 0; r < 4; ++r) gload_lds16(Ag + (size_t)r * 262144, Al + r * 8192);
        #pragma unroll
        for (int r = 0; r < 4; ++r) gload_lds16(Bg + (size_t)r * 262144, Bl + r * 8192);
    };

    // per-K-step body, c = buffer index (compile-time 0/1 via unroll 2)
    auto ldsA = [&](const char* Ab, int qm, int i, int ks) -> bf16x8 {
        const int R = wr * 128 + qm * 64 + i * 16 + lr;
        const int cb = ks * 64 + lkb;
        return *(const bf16x8*)(Ab + R * 128 + (cb ^ ((R & 7) << 4)));
    };
    auto ldsB = [&](const char* Bb, int qn, int j, int ks) -> bf16x8 {
        const int R = wc * 64 + qn * 32 + j * 16 + lr;
        const int cb = ks * 64 + lkb;
        return *(const bf16x8*)(Bb + R * 128 + (cb ^ ((R & 7) << 4)));
    };

    auto window1 = [&](int c) {
        const char* Ab = smem + c * 65536;
        const char* Bb = smem + c * 65536 + 32768;
        // read A half 0 + B half 0
        #pragma unroll
        for (int i = 0; i < 4; ++i) { aA[i][0] = ldsA(Ab, 0, i, 0); aA[i][1] = ldsA(Ab, 0, i, 1); }
        #pragma unroll
        for (int j = 0; j < 2; ++j) { bB[0][j][0] = ldsB(Bb, 0, j, 0); bB[0][j][1] = ldsB(Bb, 0, j, 1); }
        // q00
        __builtin_amdgcn_s_setprio(1);
        #pragma unroll
        for (int ks = 0; ks < 2; ++ks)
            #pragma unroll
            for (int i = 0; i < 4; ++i)
                #pragma unroll
                for (int j = 0; j < 2; ++j)
                    acc[0][0][i][j] = __builtin_amdgcn_mfma_f32_16x16x32_bf16(
                        aA[i][ks], bB[0][j][ks], acc[0][0][i][j], 0, 0, 0);
        __builtin_amdgcn_s_setprio(0);
        // read B half 1 (drains under q00/q01)
        #pragma unroll
        for (int j = 0; j < 2; ++j) { bB[1][j][0] = ldsB(Bb, 1, j, 0); bB[1][j][1] = ldsB(Bb, 1, j, 1); }
        // q01 (uses A0 still in aA)
        __builtin_amdgcn_s_setprio(1);
        #pragma unroll
        for (int ks = 0; ks < 2; ++ks)
            #pragma unroll
            for (int i = 0; i < 4; ++i)
                #pragma unroll
                for (int j = 0; j < 2; ++j)
                    acc[0][1][i][j] = __builtin_amdgcn_mfma_f32_16x16x32_bf16(
                        aA[i][ks], bB[1][j][ks], acc[0][1][i][j], 0, 0, 0);
        __builtin_amdgcn_s_setprio(0);
        // read A half 1 (WAR on aA pins this after q01's issue; drains under q11)
        #pragma unroll
        for (int i = 0; i < 4; ++i) { aA[i][0] = ldsA(Ab, 1, i, 0); aA[i][1] = ldsA(Ab, 1, i, 1); }
        // q11
        __builtin_amdgcn_s_setprio(1);
        #pragma unroll
        for (int ks = 0; ks < 2; ++ks)
            #pragma unroll
            for (int i = 0; i < 4; ++i)
                #pragma unroll
                for (int j = 0; j < 2; ++j)
                    acc[1][1][i][j] = __builtin_amdgcn_mfma_f32_16x16x32_bf16(
                        aA[i][ks], bB[1][j][ks], acc[1][1][i][j], 0, 0, 0);
        __builtin_amdgcn_s_setprio(0);
    };

    auto mfma_q10 = [&]() {
        __builtin_amdgcn_s_setprio(1);
        #pragma unroll
        for (int ks = 0; ks < 2; ++ks)
            #pragma unroll
            for (int i = 0; i < 4; ++i)
                #pragma unroll
                for (int j = 0; j < 2; ++j)
                    acc[1][0][i][j] = __builtin_amdgcn_mfma_f32_16x16x32_bf16(
                        aA[i][ks], bB[0][j][ks], acc[1][0][i][j], 0, 0, 0);
        __builtin_amdgcn_s_setprio(0);
    };

    // prologue: tiles 0,1 in flight; tile 0 guaranteed landed
    stage(0, 0);
    stage(1, 1);
    asm volatile("s_waitcnt vmcnt(8)" ::: "memory");
    __builtin_amdgcn_s_barrier();

    #pragma unroll 2
    for (int t = 0; t < 62; ++t) {
        const int c = t & 1;
        window1(c);
        __builtin_amdgcn_s_barrier();          // all buf-c reads complete
        stage(c, t + 2);                       // overwrite buf c with tile t+2
        mfma_q10();
        asm volatile("s_waitcnt vmcnt(8)" ::: "memory");  // tile t+1 landed
        __builtin_amdgcn_s_barrier();
    }
    // t = 62 (buf 0): no stage; drain tile 63's loads
    window1(0);
    __builtin_amdgcn_s_barrier();
    mfma_q10();
    asm volatile("s_waitcnt vmcnt(0)" ::: "memory");
    __builtin_amdgcn_s_barrier();
    // t = 63 (buf 1): final K-step, no staging, no waits
    window1(1);
    mfma_q10();

    // epilogue: out = tanh(acc + zs[p%4][c] + bias[c])
    // C/D layout (m89): col = lane&15, row = (lane>>4)*4 + q; p%4 == q here.
    const int lq = lane >> 4;
    #pragma unroll
    for (int qn = 0; qn < 2; ++qn)
        #pragma unroll
        for (int j = 0; j < 2; ++j) {
            const int ccol = col0 + wc * 64 + qn * 32 + j * 16 + lr;
            const float bb = bias[ccol];
            float zrow[4];
            #pragma unroll
            for (int q = 0; q < 4; ++q) zrow[q] = zs[q * 2048 + ccol] + bb;
            #pragma unroll
            for (int qm = 0; qm < 2; ++qm)
                #pragma unroll
                for (int i = 0; i < 4; ++i) {
                    const int prow = row0 + wr * 128 + qm * 64 + i * 16 + lq * 4;
                    #pragma unroll
                    for (int q = 0; q < 4; ++q)
                        out[(size_t)(prow + q) * 2048 + ccol] =
                            tanh_fast(acc[qm][qn][i][j][q] + zrow[q]);
                }
        }
}

// ---------------------------------------------------------------------------
extern "C" void kernel_launch(void* const* d_in, const int* in_sizes, int n_in,
                              void* d_out, int out_size, void* d_ws, size_t ws_size,
                              hipStream_t stream) {
    const float* e1 = (const float*)d_in[0];   // (8192, 2048)
    const float* e2 = (const float*)d_in[1];   // (8192, 2048)
    const float* W  = (const float*)d_in[2];   // (2048, 2048)
    const float* V  = (const float*)d_in[3];   // (4096, 2048)
    const float* b  = (const float*)d_in[4];   // (2048,)
    float* out = (float*)d_out;                // (8192, 2048) f32

    char* ws = (char*)d_ws;
    bf16*  Xb = (bf16*)ws;                                  // 64 MiB
    bf16*  Vt = (bf16*)(ws + (size_t)64 * 1024 * 1024);     // 16 MiB
    float* zs = (float*)(ws + (size_t)80 * 1024 * 1024);    // 32 KiB

    conv_x_zs<<<8192, 256, 0, stream>>>(e1, e2, W, Xb, zs);
    conv_vt<<<2048, 256, 0, stream>>>(V, Vt);

    hipFuncSetAttribute((const void*)gemm_ep,
                        hipFuncAttributeMaxDynamicSharedMemorySize, 131072);
    gemm_ep<<<256, 512, 131072, stream>>>(Xb, Vt, zs, b, out);
}